// Round 1
// baseline (594.694 us; speedup 1.0000x reference)
//
#include <hip/hip_runtime.h>
#include <hip/hip_bf16.h>

// Problem constants (B=4, T=2048, C=1024, H=16, HD=64)
#define BB 4
#define TT 2048
#define CC 1024
#define HH 16
#define HD 64

typedef _Float16 half8 __attribute__((ext_vector_type(8)));
typedef float floatx4 __attribute__((ext_vector_type(4)));

// ---------------------------------------------------------------------------
// fp32 -> fp16 conversion, 8 elements/thread
// ---------------------------------------------------------------------------
__global__ void cvt_f32_f16(const float* __restrict__ src, _Float16* __restrict__ dst, int n) {
    int i = (blockIdx.x * blockDim.x + threadIdx.x) * 8;
    if (i < n) {
        float4 v0 = *(const float4*)(src + i);
        float4 v1 = *(const float4*)(src + i + 4);
        half8 h;
        h[0] = (_Float16)v0.x; h[1] = (_Float16)v0.y; h[2] = (_Float16)v0.z; h[3] = (_Float16)v0.w;
        h[4] = (_Float16)v1.x; h[5] = (_Float16)v1.y; h[6] = (_Float16)v1.z; h[7] = (_Float16)v1.w;
        *(half8*)(dst + i) = h;
    }
}

// ---------------------------------------------------------------------------
// NT GEMM: C[m][n] = sum_k A[m][k]*Bw[n][k] + bias[n]
// 128x128 tile, BK=32, 256 threads (4 waves, 2x2), mfma_f32_16x16x32_f16.
// EPI=0: scatter epilogue -> Q(,scaled 1/8)/K/V fp16 in [B*H, T, 64] layout
// EPI=1: fp32 epilogue -> c_out[m*N+n]
// ---------------------------------------------------------------------------
template <int EPI>
__global__ __launch_bounds__(256) void hgemm_nt(
    const _Float16* __restrict__ A, const _Float16* __restrict__ Bw,
    const float* __restrict__ bias,
    _Float16* __restrict__ q_out, _Float16* __restrict__ k_out, _Float16* __restrict__ v_out,
    float* __restrict__ c_out,
    int M, int N, int K)
{
    __shared__ __attribute__((aligned(16))) _Float16 As[128][40]; // +8 pad: 2-way max bank alias
    __shared__ __attribute__((aligned(16))) _Float16 Bs[128][40];

    const int tid  = threadIdx.x;
    const int lane = tid & 63;
    const int wave = tid >> 6;
    const int quad = lane >> 4;
    const int lc   = lane & 15;
    const int wr   = wave >> 1, wc = wave & 1;
    const size_t bm = (size_t)blockIdx.y * 128;
    const size_t bn = (size_t)blockIdx.x * 128;

    // staging: each thread moves one 16B chunk of each 64-row half of A and B
    const int r0 = tid >> 2;        // 0..63
    const int ck = (tid & 3) * 8;   // 0,8,16,24

    const _Float16* Ap0 = A + (bm + r0) * (size_t)K + ck;
    const _Float16* Ap1 = A + (bm + 64 + r0) * (size_t)K + ck;
    const _Float16* Bp0 = Bw + (bn + r0) * (size_t)K + ck;
    const _Float16* Bp1 = Bw + (bn + 64 + r0) * (size_t)K + ck;

    floatx4 acc[4][4] = {};

    for (int kk = 0; kk < K; kk += 32) {
        half8 a0 = *(const half8*)(Ap0 + kk);
        half8 a1 = *(const half8*)(Ap1 + kk);
        half8 b0 = *(const half8*)(Bp0 + kk);
        half8 b1 = *(const half8*)(Bp1 + kk);
        __syncthreads();  // previous tile fully consumed
        *(half8*)&As[r0][ck]      = a0;
        *(half8*)&As[64 + r0][ck] = a1;
        *(half8*)&Bs[r0][ck]      = b0;
        *(half8*)&Bs[64 + r0][ck] = b1;
        __syncthreads();  // staging visible

        half8 af[4], bf[4];
#pragma unroll
        for (int mt = 0; mt < 4; mt++) af[mt] = *(const half8*)&As[wr * 64 + mt * 16 + lc][quad * 8];
#pragma unroll
        for (int nt = 0; nt < 4; nt++) bf[nt] = *(const half8*)&Bs[wc * 64 + nt * 16 + lc][quad * 8];
#pragma unroll
        for (int mt = 0; mt < 4; mt++)
#pragma unroll
            for (int nt = 0; nt < 4; nt++)
                acc[mt][nt] = __builtin_amdgcn_mfma_f32_16x16x32_f16(af[mt], bf[nt], acc[mt][nt], 0, 0, 0);
    }

    // epilogue: C/D layout row = quad*4+r, col = lc (m89-verified)
#pragma unroll
    for (int mt = 0; mt < 4; mt++) {
        int mbase = (int)bm + wr * 64 + mt * 16 + quad * 4;
#pragma unroll
        for (int nt = 0; nt < 4; nt++) {
            int n = (int)bn + wc * 64 + nt * 16 + lc;
            float bv = bias[n];
#pragma unroll
            for (int r = 0; r < 4; r++) {
                float v = acc[mt][nt][r] + bv;
                int mm = mbase + r;
                if (EPI == 0) {
                    int seg = n >> 10;        // 0=Q 1=K 2=V
                    int cm  = n & 1023;
                    int h = cm >> 6, d = cm & 63;
                    int bb = mm >> 11, t = mm & 2047;   // T=2048
                    size_t dst = (((size_t)(bb * HH + h)) * TT + t) * HD + d;
                    if (seg == 0)      q_out[dst] = (_Float16)(v * 0.125f);  // fold 1/sqrt(HD)
                    else if (seg == 1) k_out[dst] = (_Float16)v;
                    else               v_out[dst] = (_Float16)v;
                } else {
                    c_out[(size_t)mm * N + n] = v;
                }
            }
        }
    }
}

// ---------------------------------------------------------------------------
// Flash attention: grid (B*H, T/64). Block = 256 thr = 4 waves; wave owns 16
// q-rows. Key tiles of 32. Q pre-scaled. Writes O as [B*T, C] fp16 (col=h*64+d).
// ---------------------------------------------------------------------------
__global__ __launch_bounds__(256) void attn_flash(
    const _Float16* __restrict__ Qp, const _Float16* __restrict__ Kp,
    const _Float16* __restrict__ Vp, _Float16* __restrict__ Op)
{
    __shared__ __attribute__((aligned(16))) _Float16 Ks[32][72];     // [key][dim], +8 pad
    __shared__ __attribute__((aligned(16))) _Float16 Vts[64][40];    // [dim][key], +8 pad
    __shared__ __attribute__((aligned(16))) _Float16 Ps[4][16][40];  // wave-private P

    const int bh   = blockIdx.x;   // 0..63
    const int qt   = blockIdx.y;   // 0..31
    const int tid  = threadIdx.x;
    const int lane = tid & 63;
    const int wave = tid >> 6;
    const int quad = lane >> 4;
    const int lc   = lane & 15;

    const size_t hb = (size_t)bh * TT * HD;
    const _Float16* Qh = Qp + hb;
    const _Float16* Kh = Kp + hb;
    const _Float16* Vh = Vp + hb;

    // Q tile 16x64 in A-layout (m=lc, k=quad*8+j), resident whole kernel
    const int qrow = qt * 64 + wave * 16 + lc;
    half8 aq0 = *(const half8*)(Qh + (size_t)qrow * HD + quad * 8);
    half8 aq1 = *(const half8*)(Qh + (size_t)qrow * HD + 32 + quad * 8);

    floatx4 o0 = {}, o1 = {}, o2 = {}, o3 = {};   // O in C-layout, dims [0,16,32,48)+lc
    float m_i[4] = {-1e30f, -1e30f, -1e30f, -1e30f};
    float l_i[4] = {0.f, 0.f, 0.f, 0.f};

    const int srow = tid >> 3;       // 0..31 (key within tile)
    const int sck  = (tid & 7) * 8;  // 0..56 (dim chunk)

    for (int kt = 0; kt < TT; kt += 32) {
        half8 kv = *(const half8*)(Kh + (size_t)(kt + srow) * HD + sck);
        half8 vv = *(const half8*)(Vh + (size_t)(kt + srow) * HD + sck);
        __syncthreads();  // previous tile consumed
        *(half8*)&Ks[srow][sck] = kv;
#pragma unroll
        for (int j = 0; j < 8; j++) Vts[sck + j][srow] = vv[j];  // transpose V
        __syncthreads();  // staging visible

        // S = Q K^T over 32 keys: two 16-key column groups, K-dim split 0-31/32-63
        floatx4 s0 = {}, s1 = {};
        {
            half8 k0 = *(const half8*)&Ks[lc][quad * 8];
            half8 k1 = *(const half8*)&Ks[lc][32 + quad * 8];
            s0 = __builtin_amdgcn_mfma_f32_16x16x32_f16(aq0, k0, s0, 0, 0, 0);
            s0 = __builtin_amdgcn_mfma_f32_16x16x32_f16(aq1, k1, s0, 0, 0, 0);
            half8 k2 = *(const half8*)&Ks[16 + lc][quad * 8];
            half8 k3 = *(const half8*)&Ks[16 + lc][32 + quad * 8];
            s1 = __builtin_amdgcn_mfma_f32_16x16x32_f16(aq0, k2, s1, 0, 0, 0);
            s1 = __builtin_amdgcn_mfma_f32_16x16x32_f16(aq1, k3, s1, 0, 0, 0);
        }

        // online softmax; lane's reg r <-> q-row quad*4+r; cols spread over lc
        float mx[4], p0[4], p1[4], al[4], rs[4];
#pragma unroll
        for (int r = 0; r < 4; r++) mx[r] = fmaxf(s0[r], s1[r]);
#pragma unroll
        for (int off = 8; off >= 1; off >>= 1)
#pragma unroll
            for (int r = 0; r < 4; r++) mx[r] = fmaxf(mx[r], __shfl_xor(mx[r], off));
#pragma unroll
        for (int r = 0; r < 4; r++) {
            float mnew = fmaxf(m_i[r], mx[r]);
            al[r] = __expf(m_i[r] - mnew);
            m_i[r] = mnew;
            p0[r] = __expf(s0[r] - mnew);
            p1[r] = __expf(s1[r] - mnew);
            rs[r] = p0[r] + p1[r];
        }
#pragma unroll
        for (int off = 8; off >= 1; off >>= 1)
#pragma unroll
            for (int r = 0; r < 4; r++) rs[r] += __shfl_xor(rs[r], off);
#pragma unroll
        for (int r = 0; r < 4; r++) {
            l_i[r] = l_i[r] * al[r] + rs[r];
            o0[r] *= al[r]; o1[r] *= al[r]; o2[r] *= al[r]; o3[r] *= al[r];
        }

        // P: C-layout -> A-layout via wave-private LDS round trip (m120 pattern)
#pragma unroll
        for (int r = 0; r < 4; r++) {
            Ps[wave][quad * 4 + r][lc]      = (_Float16)p0[r];
            Ps[wave][quad * 4 + r][16 + lc] = (_Float16)p1[r];
        }
        __threadfence_block();  // order wave's own LDS write->read

        half8 pa = *(const half8*)&Ps[wave][lc][quad * 8];  // A[m=lc][k(key)=quad*8+j]
        half8 v0 = *(const half8*)&Vts[lc][quad * 8];       // B[k(key)][n(dim)=0..15]
        half8 v1 = *(const half8*)&Vts[16 + lc][quad * 8];
        half8 v2 = *(const half8*)&Vts[32 + lc][quad * 8];
        half8 v3 = *(const half8*)&Vts[48 + lc][quad * 8];
        o0 = __builtin_amdgcn_mfma_f32_16x16x32_f16(pa, v0, o0, 0, 0, 0);
        o1 = __builtin_amdgcn_mfma_f32_16x16x32_f16(pa, v1, o1, 0, 0, 0);
        o2 = __builtin_amdgcn_mfma_f32_16x16x32_f16(pa, v2, o2, 0, 0, 0);
        o3 = __builtin_amdgcn_mfma_f32_16x16x32_f16(pa, v3, o3, 0, 0, 0);
    }

    float inv[4];
#pragma unroll
    for (int r = 0; r < 4; r++) inv[r] = 1.0f / l_i[r];
    const int b = bh >> 4, h = bh & 15;
#pragma unroll
    for (int r = 0; r < 4; r++) {
        int t = qt * 64 + wave * 16 + quad * 4 + r;
        size_t base = ((size_t)(b * TT + t)) * CC + h * HD;
        Op[base + lc]      = (_Float16)(o0[r] * inv[r]);
        Op[base + 16 + lc] = (_Float16)(o1[r] * inv[r]);
        Op[base + 32 + lc] = (_Float16)(o2[r] * inv[r]);
        Op[base + 48 + lc] = (_Float16)(o3[r] * inv[r]);
    }
}

// ---------------------------------------------------------------------------
extern "C" void kernel_launch(void* const* d_in, const int* in_sizes, int n_in,
                              void* d_out, int out_size, void* d_ws, size_t ws_size,
                              hipStream_t stream) {
    const float* x      = (const float*)d_in[0];  // [B,T,C]
    const float* W_attn = (const float*)d_in[1];  // [3C,C]
    const float* b_attn = (const float*)d_in[2];  // [3C]
    const float* W_proj = (const float*)d_in[3];  // [C,C]
    const float* b_proj = (const float*)d_in[4];  // [C]
    float* out = (float*)d_out;

    // workspace layout (bytes), all 16B-aligned
    const size_t SZ_XH  = (size_t)BB * TT * CC * 2;        // 16 MiB
    const size_t SZ_WA  = (size_t)3 * CC * CC * 2;         // 6 MiB
    const size_t SZ_WP  = (size_t)CC * CC * 2;             // 2 MiB
    const size_t SZ_QKV = (size_t)BB * HH * TT * HD * 2;   // 16 MiB each
    size_t off = 0;
    _Float16* xh  = (_Float16*)((char*)d_ws + off); off += SZ_XH;
    _Float16* wah = (_Float16*)((char*)d_ws + off); off += SZ_WA;
    _Float16* wph = (_Float16*)((char*)d_ws + off); off += SZ_WP;
    _Float16* Qh  = (_Float16*)((char*)d_ws + off); off += SZ_QKV;
    _Float16* Kh  = (_Float16*)((char*)d_ws + off); off += SZ_QKV;
    _Float16* Vh  = (_Float16*)((char*)d_ws + off); off += SZ_QKV;
    _Float16* Ah  = (_Float16*)((char*)d_ws + off); off += SZ_XH;
    if (ws_size < off) return;  // signal: output stays poisoned/zero

    const int NX = BB * TT * CC;       // 8388608
    const int NWA = 3 * CC * CC;       // 3145728
    const int NWP = CC * CC;           // 1048576
    cvt_f32_f16<<<NX / 8 / 256, 256, 0, stream>>>(x, xh, NX);
    cvt_f32_f16<<<NWA / 8 / 256, 256, 0, stream>>>(W_attn, wah, NWA);
    cvt_f32_f16<<<NWP / 8 / 256, 256, 0, stream>>>(W_proj, wph, NWP);

    // QKV projection: M=8192, N=3072, K=1024
    hgemm_nt<0><<<dim3(3 * CC / 128, BB * TT / 128), 256, 0, stream>>>(
        xh, wah, b_attn, Qh, Kh, Vh, nullptr, BB * TT, 3 * CC, CC);

    attn_flash<<<dim3(BB * HH, TT / 64), 256, 0, stream>>>(Qh, Kh, Vh, Ah);

    // output projection: M=8192, N=1024, K=1024
    hgemm_nt<1><<<dim3(CC / 128, BB * TT / 128), 256, 0, stream>>>(
        Ah, wph, b_proj, nullptr, nullptr, nullptr, out, BB * TT, CC, CC);
}

// Round 2
// 362.753 us; speedup vs baseline: 1.6394x; 1.6394x over previous
//
#include <hip/hip_runtime.h>
#include <hip/hip_bf16.h>

// Problem constants (B=4, T=2048, C=1024, H=16, HD=64)
#define BB 4
#define TT 2048
#define CC 1024
#define HH 16
#define HD 64

typedef _Float16 half8 __attribute__((ext_vector_type(8)));
typedef _Float16 half4 __attribute__((ext_vector_type(4)));
typedef float floatx4 __attribute__((ext_vector_type(4)));

// ---------------------------------------------------------------------------
// fp32 -> fp16 conversion, 8 elements/thread
// ---------------------------------------------------------------------------
__global__ void cvt_f32_f16(const float* __restrict__ src, _Float16* __restrict__ dst, int n) {
    int i = (blockIdx.x * blockDim.x + threadIdx.x) * 8;
    if (i < n) {
        float4 v0 = *(const float4*)(src + i);
        float4 v1 = *(const float4*)(src + i + 4);
        half8 h;
        h[0] = (_Float16)v0.x; h[1] = (_Float16)v0.y; h[2] = (_Float16)v0.z; h[3] = (_Float16)v0.w;
        h[4] = (_Float16)v1.x; h[5] = (_Float16)v1.y; h[6] = (_Float16)v1.z; h[7] = (_Float16)v1.w;
        *(half8*)(dst + i) = h;
    }
}

// ---------------------------------------------------------------------------
// NT GEMM: C[m][n] = sum_k A[m][k]*Bw[n][k] + bias[n]
// 128x128 tile, BK=32, 256 threads (4 waves, 2x2), mfma_f32_16x16x32_f16.
// EPI=0: scatter epilogue -> Q(scaled 0.125*log2e)/K/V fp16 [B*H, T, 64]
// EPI=1: fp32 epilogue -> c_out[m*N+n]
// ---------------------------------------------------------------------------
template <int EPI>
__global__ __launch_bounds__(256) void hgemm_nt(
    const _Float16* __restrict__ A, const _Float16* __restrict__ Bw,
    const float* __restrict__ bias,
    _Float16* __restrict__ q_out, _Float16* __restrict__ k_out, _Float16* __restrict__ v_out,
    float* __restrict__ c_out,
    int M, int N, int K)
{
    __shared__ __attribute__((aligned(16))) _Float16 As[128][40];
    __shared__ __attribute__((aligned(16))) _Float16 Bs[128][40];

    const int tid  = threadIdx.x;
    const int lane = tid & 63;
    const int wave = tid >> 6;
    const int quad = lane >> 4;
    const int lc   = lane & 15;
    const int wr   = wave >> 1, wc = wave & 1;
    const size_t bm = (size_t)blockIdx.y * 128;
    const size_t bn = (size_t)blockIdx.x * 128;

    const int r0 = tid >> 2;        // 0..63
    const int ck = (tid & 3) * 8;   // 0,8,16,24

    const _Float16* Ap0 = A + (bm + r0) * (size_t)K + ck;
    const _Float16* Ap1 = A + (bm + 64 + r0) * (size_t)K + ck;
    const _Float16* Bp0 = Bw + (bn + r0) * (size_t)K + ck;
    const _Float16* Bp1 = Bw + (bn + 64 + r0) * (size_t)K + ck;

    floatx4 acc[4][4] = {};

    for (int kk = 0; kk < K; kk += 32) {
        half8 a0 = *(const half8*)(Ap0 + kk);
        half8 a1 = *(const half8*)(Ap1 + kk);
        half8 b0 = *(const half8*)(Bp0 + kk);
        half8 b1 = *(const half8*)(Bp1 + kk);
        __syncthreads();
        *(half8*)&As[r0][ck]      = a0;
        *(half8*)&As[64 + r0][ck] = a1;
        *(half8*)&Bs[r0][ck]      = b0;
        *(half8*)&Bs[64 + r0][ck] = b1;
        __syncthreads();

        half8 af[4], bf[4];
#pragma unroll
        for (int mt = 0; mt < 4; mt++) af[mt] = *(const half8*)&As[wr * 64 + mt * 16 + lc][quad * 8];
#pragma unroll
        for (int nt = 0; nt < 4; nt++) bf[nt] = *(const half8*)&Bs[wc * 64 + nt * 16 + lc][quad * 8];
#pragma unroll
        for (int mt = 0; mt < 4; mt++)
#pragma unroll
            for (int nt = 0; nt < 4; nt++)
                acc[mt][nt] = __builtin_amdgcn_mfma_f32_16x16x32_f16(af[mt], bf[nt], acc[mt][nt], 0, 0, 0);
    }

#pragma unroll
    for (int mt = 0; mt < 4; mt++) {
        int mbase = (int)bm + wr * 64 + mt * 16 + quad * 4;
#pragma unroll
        for (int nt = 0; nt < 4; nt++) {
            int n = (int)bn + wc * 64 + nt * 16 + lc;
            float bv = bias[n];
#pragma unroll
            for (int r = 0; r < 4; r++) {
                float v = acc[mt][nt][r] + bv;
                int mm = mbase + r;
                if (EPI == 0) {
                    int seg = n >> 10;        // 0=Q 1=K 2=V
                    int cm  = n & 1023;
                    int h = cm >> 6, d = cm & 63;
                    int bb = mm >> 11, t = mm & 2047;
                    size_t dst = (((size_t)(bb * HH + h)) * TT + t) * HD + d;
                    // fold 1/sqrt(HD) * log2(e) into Q for exp2-based softmax
                    if (seg == 0)      q_out[dst] = (_Float16)(v * 0.18033688f);
                    else if (seg == 1) k_out[dst] = (_Float16)v;
                    else               v_out[dst] = (_Float16)v;
                } else {
                    c_out[(size_t)mm * N + n] = v;
                }
            }
        }
    }
}

// ---------------------------------------------------------------------------
// Flash attention, S^T formulation. Grid (B*H, T/64), 256 thr = 4 waves,
// each wave owns 16 queries. Key tile = 64.
//  S^T = K*Q^T via mfma_f32_16x16x32_f16 (A=K rows, B=Q rows, no transposes)
//  P^T (C-layout) == B-frag of mfma_f32_16x16x16_f16 -> PV with zero relayout
//  O^T += V^T * P^T ; V^T staged as key-pair-packed words, conflict-free.
// ---------------------------------------------------------------------------
__global__ __launch_bounds__(256) void attn_flash(
    const _Float16* __restrict__ Qp, const _Float16* __restrict__ Kp,
    const _Float16* __restrict__ Vp, _Float16* __restrict__ Op)
{
    __shared__ __attribute__((aligned(16))) _Float16 Ks[64][72];  // [key][dim], pad 8
    __shared__ unsigned int VtsW[64 * 33];  // [dim][keypair word], pad 1 word

    const int bh   = blockIdx.x;   // 0..63 (b*16+h)
    const int qt   = blockIdx.y;   // 0..31
    const int tid  = threadIdx.x;
    const int lane = tid & 63;
    const int wave = tid >> 6;
    const int quad = lane >> 4;
    const int lc   = lane & 15;

    const size_t hb = (size_t)bh * TT * HD;
    const _Float16* Kh = Kp + hb;
    const _Float16* Vh = Vp + hb;

    // Q B-fragment: B[k=dim=quad*8+j][n=q=lc], resident whole kernel
    const int qrow = qt * 64 + wave * 16 + lc;
    half8 bq0 = *(const half8*)(Qp + hb + (size_t)qrow * HD + quad * 8);
    half8 bq1 = *(const half8*)(Qp + hb + (size_t)qrow * HD + 32 + quad * 8);

    floatx4 o[4] = {};           // O^T: dim = dt*16 + quad*4 + r, q = lc
    float m_i = -1e30f, l_i = 0.f;

    // staging maps
    const int sk  = tid >> 2;          // K: key 0..63
    const int sc0 = (tid & 3) * 16;    // K: dim chunk base
    const int vkp = tid >> 3;          // V: key pair 0..31
    const int vd0 = (tid & 7) * 8;     // V: dim chunk base

    const _Float16* Kg  = Kh + (size_t)sk * HD + sc0;
    const _Float16* Vg0 = Vh + (size_t)(2 * vkp) * HD + vd0;
    const _Float16* Vg1 = Vh + (size_t)(2 * vkp + 1) * HD + vd0;

    for (int kt = 0; kt < TT; kt += 64) {
        const size_t koff = (size_t)kt * HD;
        half8 kv0 = *(const half8*)(Kg + koff);
        half8 kv1 = *(const half8*)(Kg + koff + 8);
        half8 vv0 = *(const half8*)(Vg0 + koff);
        half8 vv1 = *(const half8*)(Vg1 + koff);
        __syncthreads();  // previous tile fully consumed
        *(half8*)&Ks[sk][sc0]     = kv0;
        *(half8*)&Ks[sk][sc0 + 8] = kv1;
        {
            union { half8 h; unsigned short us[8]; } ua, ub;
            ua.h = vv0; ub.h = vv1;
#pragma unroll
            for (int j = 0; j < 8; j++)
                VtsW[(vd0 + j) * 33 + vkp] =
                    (unsigned)ua.us[j] | ((unsigned)ub.us[j] << 16);
        }
        __syncthreads();  // staging visible

        // ---- S^T = K * Q^T : 4 keytiles x 2 dim-halves ----
        floatx4 s[4];
        const floatx4 zf = {0.f, 0.f, 0.f, 0.f};
#pragma unroll
        for (int m = 0; m < 4; m++) {
            half8 a0 = *(const half8*)&Ks[m * 16 + lc][quad * 8];
            half8 a1 = *(const half8*)&Ks[m * 16 + lc][32 + quad * 8];
            s[m] = __builtin_amdgcn_mfma_f32_16x16x32_f16(a0, bq0, zf, 0, 0, 0);
            s[m] = __builtin_amdgcn_mfma_f32_16x16x32_f16(a1, bq1, s[m], 0, 0, 0);
        }

        // ---- online softmax (exp2-based; scale folded into Q) ----
        float mx = s[0][0];
#pragma unroll
        for (int m = 0; m < 4; m++)
#pragma unroll
            for (int r = 0; r < 4; r++) mx = fmaxf(mx, s[m][r]);
        mx = fmaxf(mx, __shfl_xor(mx, 16));
        mx = fmaxf(mx, __shfl_xor(mx, 32));
        float mnew = fmaxf(m_i, mx);
        float al = exp2f(m_i - mnew);
        m_i = mnew;
        float rs = 0.f;
        float p[4][4];
#pragma unroll
        for (int m = 0; m < 4; m++)
#pragma unroll
            for (int r = 0; r < 4; r++) { p[m][r] = exp2f(s[m][r] - mnew); rs += p[m][r]; }
        rs += __shfl_xor(rs, 16);
        rs += __shfl_xor(rs, 32);
        l_i = l_i * al + rs;
#pragma unroll
        for (int dt = 0; dt < 4; dt++) o[dt] *= al;

        // P^T fp16: C regs (key=quad*4+r, q=lc) == 16x16x16 B-frag directly
        half4 pf[4];
#pragma unroll
        for (int m = 0; m < 4; m++) {
            half4 t;
            t[0] = (_Float16)p[m][0]; t[1] = (_Float16)p[m][1];
            t[2] = (_Float16)p[m][2]; t[3] = (_Float16)p[m][3];
            pf[m] = t;
        }

        // ---- O^T += V^T * P^T : 4 dimtiles x 4 keytiles ----
#pragma unroll
        for (int dt = 0; dt < 4; dt++) {
            const unsigned int* vr = &VtsW[(dt * 16 + lc) * 33];
#pragma unroll
            for (int m = 0; m < 4; m++) {
                union { unsigned int u[2]; half4 h; } va;
                va.u[0] = vr[m * 8 + 2 * quad];
                va.u[1] = vr[m * 8 + 2 * quad + 1];
                o[dt] = __builtin_amdgcn_mfma_f32_16x16x16f16(va.h, pf[m], o[dt], 0, 0, 0);
            }
        }
    }

    // epilogue: O^T reg (dt, r) -> t=qrow, dim = dt*16 + quad*4 + r
    float inv = 1.0f / l_i;
    const int b = bh >> 4, h = bh & 15;
    size_t base = ((size_t)(b * TT + qrow)) * CC + h * HD;
#pragma unroll
    for (int dt = 0; dt < 4; dt++) {
        half4 hv;
#pragma unroll
        for (int r = 0; r < 4; r++) hv[r] = (_Float16)(o[dt][r] * inv);
        *(half4*)(Op + base + dt * 16 + quad * 4) = hv;
    }
}

// ---------------------------------------------------------------------------
extern "C" void kernel_launch(void* const* d_in, const int* in_sizes, int n_in,
                              void* d_out, int out_size, void* d_ws, size_t ws_size,
                              hipStream_t stream) {
    const float* x      = (const float*)d_in[0];  // [B,T,C]
    const float* W_attn = (const float*)d_in[1];  // [3C,C]
    const float* b_attn = (const float*)d_in[2];  // [3C]
    const float* W_proj = (const float*)d_in[3];  // [C,C]
    const float* b_proj = (const float*)d_in[4];  // [C]
    float* out = (float*)d_out;

    const size_t SZ_XH  = (size_t)BB * TT * CC * 2;
    const size_t SZ_WA  = (size_t)3 * CC * CC * 2;
    const size_t SZ_WP  = (size_t)CC * CC * 2;
    const size_t SZ_QKV = (size_t)BB * HH * TT * HD * 2;
    size_t off = 0;
    _Float16* xh  = (_Float16*)((char*)d_ws + off); off += SZ_XH;
    _Float16* wah = (_Float16*)((char*)d_ws + off); off += SZ_WA;
    _Float16* wph = (_Float16*)((char*)d_ws + off); off += SZ_WP;
    _Float16* Qh  = (_Float16*)((char*)d_ws + off); off += SZ_QKV;
    _Float16* Kh  = (_Float16*)((char*)d_ws + off); off += SZ_QKV;
    _Float16* Vh  = (_Float16*)((char*)d_ws + off); off += SZ_QKV;
    _Float16* Ah  = (_Float16*)((char*)d_ws + off); off += SZ_XH;
    if (ws_size < off) return;

    const int NX  = BB * TT * CC;
    const int NWA = 3 * CC * CC;
    const int NWP = CC * CC;
    cvt_f32_f16<<<NX / 8 / 256, 256, 0, stream>>>(x, xh, NX);
    cvt_f32_f16<<<NWA / 8 / 256, 256, 0, stream>>>(W_attn, wah, NWA);
    cvt_f32_f16<<<NWP / 8 / 256, 256, 0, stream>>>(W_proj, wph, NWP);

    hgemm_nt<0><<<dim3(3 * CC / 128, BB * TT / 128), 256, 0, stream>>>(
        xh, wah, b_attn, Qh, Kh, Vh, nullptr, BB * TT, 3 * CC, CC);

    attn_flash<<<dim3(BB * HH, TT / 64), 256, 0, stream>>>(Qh, Kh, Vh, Ah);

    hgemm_nt<1><<<dim3(CC / 128, BB * TT / 128), 256, 0, stream>>>(
        Ah, wph, b_proj, nullptr, nullptr, nullptr, out, BB * TT, CC, CC);
}

// Round 3
// 348.286 us; speedup vs baseline: 1.7075x; 1.0415x over previous
//
#include <hip/hip_runtime.h>
#include <hip/hip_bf16.h>

// Problem constants (B=4, T=2048, C=1024, H=16, HD=64)
#define BB 4
#define TT 2048
#define CC 1024
#define HH 16
#define HD 64

typedef _Float16 half8 __attribute__((ext_vector_type(8)));
typedef _Float16 half4 __attribute__((ext_vector_type(4)));
typedef _Float16 half2_t __attribute__((ext_vector_type(2)));
typedef float floatx4 __attribute__((ext_vector_type(4)));

// async global->LDS, 16B per lane (dest = wave-uniform base + lane*16)
__device__ __forceinline__ void async_cp16(const void* g, void* l) {
    __builtin_amdgcn_global_load_lds(
        (const __attribute__((address_space(1))) unsigned int*)g,
        (__attribute__((address_space(3))) unsigned int*)l,
        16, 0, 0);
}

// ---------------------------------------------------------------------------
// fp32 -> fp16 conversion, 8 elements/thread
// ---------------------------------------------------------------------------
__global__ void cvt_f32_f16(const float* __restrict__ src, _Float16* __restrict__ dst, int n) {
    int i = (blockIdx.x * blockDim.x + threadIdx.x) * 8;
    if (i < n) {
        float4 v0 = *(const float4*)(src + i);
        float4 v1 = *(const float4*)(src + i + 4);
        half8 h;
        h[0] = (_Float16)v0.x; h[1] = (_Float16)v0.y; h[2] = (_Float16)v0.z; h[3] = (_Float16)v0.w;
        h[4] = (_Float16)v1.x; h[5] = (_Float16)v1.y; h[6] = (_Float16)v1.z; h[7] = (_Float16)v1.w;
        *(half8*)(dst + i) = h;
    }
}

// ---------------------------------------------------------------------------
// NT GEMM, m97 structure: C[m][n] = sum_k A[m][k]*Bw[n][k] + bias[n]
// 128x128 tile, BK=32, 256 thr (4 waves 2x2), global_load_lds width-16
// staging into packed [128][32] LDS. mfma_f32_16x16x32_f16.
// EPI=0: scatter -> Q(scaled 0.125*log2e)/K/V fp16 [B*H, T, 64]
// EPI=1: fp32 -> c_out[m*N+n]
// ---------------------------------------------------------------------------
template <int EPI>
__global__ __launch_bounds__(256) void hgemm_nt(
    const _Float16* __restrict__ A, const _Float16* __restrict__ Bw,
    const float* __restrict__ bias,
    _Float16* __restrict__ q_out, _Float16* __restrict__ k_out, _Float16* __restrict__ v_out,
    float* __restrict__ c_out,
    int M, int N, int K)
{
    __shared__ __attribute__((aligned(16))) _Float16 As[128 * 32];  // packed, 8KB
    __shared__ __attribute__((aligned(16))) _Float16 Bs[128 * 32];

    const int tid  = threadIdx.x;
    const int lane = tid & 63;
    const int wave = tid >> 6;
    const int quad = lane >> 4;
    const int lc   = lane & 15;
    const int wr   = wave >> 1, wc = wave & 1;
    const size_t bm = (size_t)blockIdx.y * 128;
    const size_t bn = (size_t)blockIdx.x * 128;

    // staging map: thread t covers LDS halves [t*8, t*8+8) of each 64-row half
    const int r0 = tid >> 2;        // 0..63
    const int ck = (tid & 3) * 8;   // 0,8,16,24

    const _Float16* Ap0 = A + (bm + r0) * (size_t)K + ck;
    const _Float16* Ap1 = A + (bm + 64 + r0) * (size_t)K + ck;
    const _Float16* Bp0 = Bw + (bn + r0) * (size_t)K + ck;
    const _Float16* Bp1 = Bw + (bn + 64 + r0) * (size_t)K + ck;
    _Float16* lA0 = As + tid * 8;
    _Float16* lA1 = As + 2048 + tid * 8;
    _Float16* lB0 = Bs + tid * 8;
    _Float16* lB1 = Bs + 2048 + tid * 8;

    floatx4 acc[4][4] = {};

    for (int kk = 0; kk < K; kk += 32) {
        __syncthreads();  // previous tile fully consumed
        async_cp16(Ap0 + kk, lA0);
        async_cp16(Ap1 + kk, lA1);
        async_cp16(Bp0 + kk, lB0);
        async_cp16(Bp1 + kk, lB1);
        __syncthreads();  // barrier drains vmcnt -> staging visible

        half8 af[4], bf[4];
#pragma unroll
        for (int mt = 0; mt < 4; mt++) af[mt] = *(const half8*)(As + (wr * 64 + mt * 16 + lc) * 32 + quad * 8);
#pragma unroll
        for (int nt = 0; nt < 4; nt++) bf[nt] = *(const half8*)(Bs + (wc * 64 + nt * 16 + lc) * 32 + quad * 8);
#pragma unroll
        for (int mt = 0; mt < 4; mt++)
#pragma unroll
            for (int nt = 0; nt < 4; nt++)
                acc[mt][nt] = __builtin_amdgcn_mfma_f32_16x16x32_f16(af[mt], bf[nt], acc[mt][nt], 0, 0, 0);
    }

#pragma unroll
    for (int mt = 0; mt < 4; mt++) {
        int mbase = (int)bm + wr * 64 + mt * 16 + quad * 4;
#pragma unroll
        for (int nt = 0; nt < 4; nt++) {
            int n = (int)bn + wc * 64 + nt * 16 + lc;
            float bv = bias[n];
#pragma unroll
            for (int r = 0; r < 4; r++) {
                float v = acc[mt][nt][r] + bv;
                int mm = mbase + r;
                if (EPI == 0) {
                    int seg = n >> 10;        // 0=Q 1=K 2=V
                    int cm  = n & 1023;
                    int h = cm >> 6, d = cm & 63;
                    int bb = mm >> 11, t = mm & 2047;
                    size_t dst = (((size_t)(bb * HH + h)) * TT + t) * HD + d;
                    // fold 1/sqrt(HD) * log2(e) into Q for exp2-based softmax
                    if (seg == 0)      q_out[dst] = (_Float16)(v * 0.18033688f);
                    else if (seg == 1) k_out[dst] = (_Float16)v;
                    else               v_out[dst] = (_Float16)v;
                } else {
                    c_out[(size_t)mm * N + n] = v;
                }
            }
        }
    }
}

// ---------------------------------------------------------------------------
// Flash attention, S^T formulation. Grid (B*H, T/128), 512 thr = 8 waves,
// each wave owns 16 queries (q-tile 128). Key tile = 64.
//  S^T = K*Q^T (mfma 16x16x32, A=K rows, B=Q rows)
//  P^T C-regs == B-frag of mfma 16x16x16 -> PV with zero relayout
//  O^T += V^T * P^T ; V^T in Vt[64][76]: b64 frag reads conflict-free+aligned
// ---------------------------------------------------------------------------
__global__ __launch_bounds__(512) void attn_flash(
    const _Float16* __restrict__ Qp, const _Float16* __restrict__ Kp,
    const _Float16* __restrict__ Vp, _Float16* __restrict__ Op)
{
    __shared__ __attribute__((aligned(16))) _Float16 Ks[64][72];  // [key][dim]
    __shared__ __attribute__((aligned(16))) _Float16 Vt[64][76];  // [dim][key]

    const int bh   = blockIdx.x;   // 0..63 (b*16+h)
    const int qt   = blockIdx.y;   // 0..15
    const int tid  = threadIdx.x;
    const int lane = tid & 63;
    const int wave = tid >> 6;     // 0..7
    const int quad = lane >> 4;
    const int lc   = lane & 15;

    const size_t hb = (size_t)bh * TT * HD;
    const _Float16* Kh = Kp + hb;
    const _Float16* Vh = Vp + hb;

    // Q B-fragment: B[k=dim=quad*8+j][n=q=lc], resident whole kernel
    const int qrow = qt * 128 + wave * 16 + lc;
    half8 bq0 = *(const half8*)(Qp + hb + (size_t)qrow * HD + quad * 8);
    half8 bq1 = *(const half8*)(Qp + hb + (size_t)qrow * HD + 32 + quad * 8);

    floatx4 o[4] = {};           // O^T: dim = dt*16 + quad*4 + r, q = lc
    float m_i = -1e30f, l_i = 0.f;

    // staging maps (512 threads)
    const int sk  = tid >> 3;          // K: key 0..63
    const int sc0 = (tid & 7) * 8;     // K: dim chunk
    const int vkp = tid >> 4;          // V: key pair 0..31
    const int vd4 = (tid & 15) * 4;    // V: dim group 0..60

    const _Float16* Kg  = Kh + (size_t)sk * HD + sc0;
    const _Float16* Vg0 = Vh + (size_t)(2 * vkp) * HD + vd4;
    const _Float16* Vg1 = Vg0 + HD;

    for (int kt = 0; kt < TT; kt += 64) {
        const size_t koff = (size_t)kt * HD;
        half8 kv  = *(const half8*)(Kg + koff);
        half4 va0 = *(const half4*)(Vg0 + koff);
        half4 vb0 = *(const half4*)(Vg1 + koff);
        __syncthreads();  // previous tile fully consumed
        *(half8*)&Ks[sk][sc0] = kv;
#pragma unroll
        for (int j = 0; j < 4; j++) {
            half2_t w; w[0] = va0[j]; w[1] = vb0[j];
            *(half2_t*)&Vt[vd4 + j][2 * vkp] = w;
        }
        __syncthreads();  // staging visible

        // ---- S^T = K * Q^T : 4 keytiles x 2 dim-halves ----
        floatx4 s[4];
        const floatx4 zf = {0.f, 0.f, 0.f, 0.f};
#pragma unroll
        for (int m = 0; m < 4; m++) {
            half8 a0 = *(const half8*)&Ks[m * 16 + lc][quad * 8];
            half8 a1 = *(const half8*)&Ks[m * 16 + lc][32 + quad * 8];
            s[m] = __builtin_amdgcn_mfma_f32_16x16x32_f16(a0, bq0, zf, 0, 0, 0);
            s[m] = __builtin_amdgcn_mfma_f32_16x16x32_f16(a1, bq1, s[m], 0, 0, 0);
        }

        // ---- online softmax (exp2; scale folded into Q). lane = 1 query ----
        float mx = s[0][0];
#pragma unroll
        for (int m = 0; m < 4; m++)
#pragma unroll
            for (int r = 0; r < 4; r++) mx = fmaxf(mx, s[m][r]);
        mx = fmaxf(mx, __shfl_xor(mx, 16));
        mx = fmaxf(mx, __shfl_xor(mx, 32));
        float mnew = fmaxf(m_i, mx);
        float al = exp2f(m_i - mnew);
        m_i = mnew;
        float rs = 0.f;
        half4 pf[4];
#pragma unroll
        for (int m = 0; m < 4; m++) {
            float p0 = exp2f(s[m][0] - mnew);
            float p1 = exp2f(s[m][1] - mnew);
            float p2 = exp2f(s[m][2] - mnew);
            float p3 = exp2f(s[m][3] - mnew);
            rs += (p0 + p1) + (p2 + p3);
            half4 t;
            t[0] = (_Float16)p0; t[1] = (_Float16)p1;
            t[2] = (_Float16)p2; t[3] = (_Float16)p3;
            pf[m] = t;
        }
        rs += __shfl_xor(rs, 16);
        rs += __shfl_xor(rs, 32);
        l_i = l_i * al + rs;
#pragma unroll
        for (int dt = 0; dt < 4; dt++) o[dt] *= al;

        // ---- O^T += V^T * P^T : 4 dimtiles x 4 keytiles ----
#pragma unroll
        for (int dt = 0; dt < 4; dt++) {
            const _Float16* vr = &Vt[dt * 16 + lc][quad * 4];
#pragma unroll
            for (int m = 0; m < 4; m++) {
                half4 va = *(const half4*)(vr + m * 16);  // keys m*16+quad*4+{0..3}
                o[dt] = __builtin_amdgcn_mfma_f32_16x16x16f16(va, pf[m], o[dt], 0, 0, 0);
            }
        }
    }

    // epilogue: O^T reg (dt, r) -> t=qrow, dim = dt*16 + quad*4 + r
    float inv = 1.0f / l_i;
    const int b = bh >> 4, h = bh & 15;
    size_t base = ((size_t)(b * TT + qrow)) * CC + h * HD;
#pragma unroll
    for (int dt = 0; dt < 4; dt++) {
        half4 hv;
#pragma unroll
        for (int r = 0; r < 4; r++) hv[r] = (_Float16)(o[dt][r] * inv);
        *(half4*)(Op + base + dt * 16 + quad * 4) = hv;
    }
}

// ---------------------------------------------------------------------------
extern "C" void kernel_launch(void* const* d_in, const int* in_sizes, int n_in,
                              void* d_out, int out_size, void* d_ws, size_t ws_size,
                              hipStream_t stream) {
    const float* x      = (const float*)d_in[0];  // [B,T,C]
    const float* W_attn = (const float*)d_in[1];  // [3C,C]
    const float* b_attn = (const float*)d_in[2];  // [3C]
    const float* W_proj = (const float*)d_in[3];  // [C,C]
    const float* b_proj = (const float*)d_in[4];  // [C]
    float* out = (float*)d_out;

    const size_t SZ_XH  = (size_t)BB * TT * CC * 2;
    const size_t SZ_WA  = (size_t)3 * CC * CC * 2;
    const size_t SZ_WP  = (size_t)CC * CC * 2;
    const size_t SZ_QKV = (size_t)BB * HH * TT * HD * 2;
    size_t off = 0;
    _Float16* xh  = (_Float16*)((char*)d_ws + off); off += SZ_XH;
    _Float16* wah = (_Float16*)((char*)d_ws + off); off += SZ_WA;
    _Float16* wph = (_Float16*)((char*)d_ws + off); off += SZ_WP;
    _Float16* Qh  = (_Float16*)((char*)d_ws + off); off += SZ_QKV;
    _Float16* Kh  = (_Float16*)((char*)d_ws + off); off += SZ_QKV;
    _Float16* Vh  = (_Float16*)((char*)d_ws + off); off += SZ_QKV;
    _Float16* Ah  = (_Float16*)((char*)d_ws + off); off += SZ_XH;
    if (ws_size < off) return;

    const int NX  = BB * TT * CC;
    const int NWA = 3 * CC * CC;
    const int NWP = CC * CC;
    cvt_f32_f16<<<NX / 8 / 256, 256, 0, stream>>>(x, xh, NX);
    cvt_f32_f16<<<NWA / 8 / 256, 256, 0, stream>>>(W_attn, wah, NWA);
    cvt_f32_f16<<<NWP / 8 / 256, 256, 0, stream>>>(W_proj, wph, NWP);

    hgemm_nt<0><<<dim3(3 * CC / 128, BB * TT / 128), 256, 0, stream>>>(
        xh, wah, b_attn, Qh, Kh, Vh, nullptr, BB * TT, 3 * CC, CC);

    attn_flash<<<dim3(BB * HH, TT / 128), 512, 0, stream>>>(Qh, Kh, Vh, Ah);

    hgemm_nt<1><<<dim3(CC / 128, BB * TT / 128), 256, 0, stream>>>(
        Ah, wph, b_proj, nullptr, nullptr, nullptr, out, BB * TT, CC, CC);
}

// Round 4
// 326.507 us; speedup vs baseline: 1.8214x; 1.0667x over previous
//
#include <hip/hip_runtime.h>
#include <hip/hip_bf16.h>

// Problem constants (B=4, T=2048, C=1024, H=16, HD=64)
#define BB 4
#define TT 2048
#define CC 1024
#define HH 16
#define HD 64

typedef _Float16 half8 __attribute__((ext_vector_type(8)));
typedef _Float16 half4 __attribute__((ext_vector_type(4)));
typedef _Float16 half2_t __attribute__((ext_vector_type(2)));
typedef float floatx4 __attribute__((ext_vector_type(4)));

// async global->LDS, 16B per lane (dest = wave-uniform base + lane*16)
__device__ __forceinline__ void async_cp16(const void* g, void* l) {
    __builtin_amdgcn_global_load_lds(
        (const __attribute__((address_space(1))) unsigned int*)g,
        (__attribute__((address_space(3))) unsigned int*)l,
        16, 0, 0);
}

// ---------------------------------------------------------------------------
// fp32 -> fp16 conversion, 8 elements/thread
// ---------------------------------------------------------------------------
__global__ void cvt_f32_f16(const float* __restrict__ src, _Float16* __restrict__ dst, int n) {
    int i = (blockIdx.x * blockDim.x + threadIdx.x) * 8;
    if (i < n) {
        float4 v0 = *(const float4*)(src + i);
        float4 v1 = *(const float4*)(src + i + 4);
        half8 h;
        h[0] = (_Float16)v0.x; h[1] = (_Float16)v0.y; h[2] = (_Float16)v0.z; h[3] = (_Float16)v0.w;
        h[4] = (_Float16)v1.x; h[5] = (_Float16)v1.y; h[6] = (_Float16)v1.z; h[7] = (_Float16)v1.w;
        *(half8*)(dst + i) = h;
    }
}

// ---------------------------------------------------------------------------
// NT GEMM, m97 structure: C[m][n] = sum_k A[m][k]*Bw[n][k] + bias[n]
// 128x128 tile, BK=32, 256 thr (4 waves 2x2), global_load_lds width-16
// staging into packed [128][32] LDS. mfma_f32_16x16x32_f16.
// EPI=0: scatter -> Q(scaled 0.125*log2e)/K/V fp16 [B*H, T, 64]
// EPI=1: fp32 -> c_out[m*N+n]
// ---------------------------------------------------------------------------
template <int EPI>
__global__ __launch_bounds__(256) void hgemm_nt(
    const _Float16* __restrict__ A, const _Float16* __restrict__ Bw,
    const float* __restrict__ bias,
    _Float16* __restrict__ q_out, _Float16* __restrict__ k_out, _Float16* __restrict__ v_out,
    float* __restrict__ c_out,
    int M, int N, int K)
{
    __shared__ __attribute__((aligned(16))) _Float16 As[128 * 32];  // packed, 8KB
    __shared__ __attribute__((aligned(16))) _Float16 Bs[128 * 32];

    const int tid  = threadIdx.x;
    const int lane = tid & 63;
    const int wave = tid >> 6;
    const int quad = lane >> 4;
    const int lc   = lane & 15;
    const int wr   = wave >> 1, wc = wave & 1;
    const size_t bm = (size_t)blockIdx.y * 128;
    const size_t bn = (size_t)blockIdx.x * 128;

    const int r0 = tid >> 2;        // 0..63
    const int ck = (tid & 3) * 8;   // 0,8,16,24

    const _Float16* Ap0 = A + (bm + r0) * (size_t)K + ck;
    const _Float16* Ap1 = A + (bm + 64 + r0) * (size_t)K + ck;
    const _Float16* Bp0 = Bw + (bn + r0) * (size_t)K + ck;
    const _Float16* Bp1 = Bw + (bn + 64 + r0) * (size_t)K + ck;
    _Float16* lA0 = As + tid * 8;
    _Float16* lA1 = As + 2048 + tid * 8;
    _Float16* lB0 = Bs + tid * 8;
    _Float16* lB1 = Bs + 2048 + tid * 8;

    floatx4 acc[4][4] = {};

    for (int kk = 0; kk < K; kk += 32) {
        __syncthreads();  // previous tile fully consumed
        async_cp16(Ap0 + kk, lA0);
        async_cp16(Ap1 + kk, lA1);
        async_cp16(Bp0 + kk, lB0);
        async_cp16(Bp1 + kk, lB1);
        __syncthreads();  // barrier drains vmcnt -> staging visible

        half8 af[4], bf[4];
#pragma unroll
        for (int mt = 0; mt < 4; mt++) af[mt] = *(const half8*)(As + (wr * 64 + mt * 16 + lc) * 32 + quad * 8);
#pragma unroll
        for (int nt = 0; nt < 4; nt++) bf[nt] = *(const half8*)(Bs + (wc * 64 + nt * 16 + lc) * 32 + quad * 8);
#pragma unroll
        for (int mt = 0; mt < 4; mt++)
#pragma unroll
            for (int nt = 0; nt < 4; nt++)
                acc[mt][nt] = __builtin_amdgcn_mfma_f32_16x16x32_f16(af[mt], bf[nt], acc[mt][nt], 0, 0, 0);
    }

#pragma unroll
    for (int mt = 0; mt < 4; mt++) {
        int mbase = (int)bm + wr * 64 + mt * 16 + quad * 4;
#pragma unroll
        for (int nt = 0; nt < 4; nt++) {
            int n = (int)bn + wc * 64 + nt * 16 + lc;
            float bv = bias[n];
#pragma unroll
            for (int r = 0; r < 4; r++) {
                float v = acc[mt][nt][r] + bv;
                int mm = mbase + r;
                if (EPI == 0) {
                    int seg = n >> 10;        // 0=Q 1=K 2=V
                    int cm  = n & 1023;
                    int h = cm >> 6, d = cm & 63;
                    int bb = mm >> 11, t = mm & 2047;
                    size_t dst = (((size_t)(bb * HH + h)) * TT + t) * HD + d;
                    // fold 1/sqrt(HD) * log2(e) into Q for exp2-based softmax
                    if (seg == 0)      q_out[dst] = (_Float16)(v * 0.18033688f);
                    else if (seg == 1) k_out[dst] = (_Float16)v;
                    else               v_out[dst] = (_Float16)v;
                } else {
                    c_out[(size_t)mm * N + n] = v;
                }
            }
        }
    }
}

// ---------------------------------------------------------------------------
// Flash attention, S^T formulation, 32 queries/wave. Grid (B*H, T/256),
// 512 thr = 8 waves, q-block 256. Key tile = 64.
//  S^T = K*Q^T (mfma 16x16x32, A=K rows shared across both query groups)
//  P^T C-regs == B-frag of mfma 16x16x16 -> PV with zero relayout
//  O^T += V^T * P^T ; V-frags shared across both query groups.
// ---------------------------------------------------------------------------
__global__ __launch_bounds__(512) void attn_flash(
    const _Float16* __restrict__ Qp, const _Float16* __restrict__ Kp,
    const _Float16* __restrict__ Vp, _Float16* __restrict__ Op)
{
    __shared__ __attribute__((aligned(16))) _Float16 Ks[64][72];  // [key][dim]
    __shared__ __attribute__((aligned(16))) _Float16 Vt[64][76];  // [dim][key]

    const int bh   = blockIdx.x;   // 0..63 (b*16+h)
    const int qt   = blockIdx.y;   // 0..7
    const int tid  = threadIdx.x;
    const int lane = tid & 63;
    const int wave = tid >> 6;     // 0..7
    const int quad = lane >> 4;
    const int lc   = lane & 15;

    const size_t hb = (size_t)bh * TT * HD;
    const _Float16* Kh = Kp + hb;
    const _Float16* Vh = Vp + hb;

    // two query groups per wave; B-frag B[k=dim=quad*8+j][n=q=lc]
    const int q0row = qt * 256 + wave * 32 + lc;
    const int q1row = q0row + 16;
    half8 bq00 = *(const half8*)(Qp + hb + (size_t)q0row * HD + quad * 8);
    half8 bq01 = *(const half8*)(Qp + hb + (size_t)q0row * HD + 32 + quad * 8);
    half8 bq10 = *(const half8*)(Qp + hb + (size_t)q1row * HD + quad * 8);
    half8 bq11 = *(const half8*)(Qp + hb + (size_t)q1row * HD + 32 + quad * 8);

    floatx4 o0[4] = {}, o1[4] = {};  // O^T: dim = dt*16+quad*4+r, q = lc
    float m0 = -1e30f, l0 = 0.f, m1 = -1e30f, l1 = 0.f;

    // staging maps (512 threads)
    const int sk  = tid >> 3;          // K: key 0..63
    const int sc0 = (tid & 7) * 8;     // K: dim chunk
    const int vkp = tid >> 4;          // V: key pair 0..31
    const int vd4 = (tid & 15) * 4;    // V: dim group 0..60

    const _Float16* Kg  = Kh + (size_t)sk * HD + sc0;
    const _Float16* Vg0 = Vh + (size_t)(2 * vkp) * HD + vd4;
    const _Float16* Vg1 = Vg0 + HD;

    for (int kt = 0; kt < TT; kt += 64) {
        const size_t koff = (size_t)kt * HD;
        half8 kv  = *(const half8*)(Kg + koff);
        half4 va0 = *(const half4*)(Vg0 + koff);
        half4 vb0 = *(const half4*)(Vg1 + koff);
        __syncthreads();  // previous tile fully consumed
        *(half8*)&Ks[sk][sc0] = kv;
#pragma unroll
        for (int j = 0; j < 4; j++) {
            half2_t w; w[0] = va0[j]; w[1] = vb0[j];
            *(half2_t*)&Vt[vd4 + j][2 * vkp] = w;
        }
        __syncthreads();  // staging visible

        // ---- S^T = K * Q^T : 4 keytiles x 2 dim-halves x 2 q-groups ----
        floatx4 s0[4], s1[4];
        const floatx4 zf = {0.f, 0.f, 0.f, 0.f};
#pragma unroll
        for (int m = 0; m < 4; m++) {
            half8 a0 = *(const half8*)&Ks[m * 16 + lc][quad * 8];
            half8 a1 = *(const half8*)&Ks[m * 16 + lc][32 + quad * 8];
            s0[m] = __builtin_amdgcn_mfma_f32_16x16x32_f16(a0, bq00, zf, 0, 0, 0);
            s0[m] = __builtin_amdgcn_mfma_f32_16x16x32_f16(a1, bq01, s0[m], 0, 0, 0);
            s1[m] = __builtin_amdgcn_mfma_f32_16x16x32_f16(a0, bq10, zf, 0, 0, 0);
            s1[m] = __builtin_amdgcn_mfma_f32_16x16x32_f16(a1, bq11, s1[m], 0, 0, 0);
        }

        // ---- online softmax per group (exp2; scale folded into Q) ----
        half4 pf0[4], pf1[4];
        {
            float mx = s0[0][0];
#pragma unroll
            for (int m = 0; m < 4; m++)
#pragma unroll
                for (int r = 0; r < 4; r++) mx = fmaxf(mx, s0[m][r]);
            mx = fmaxf(mx, __shfl_xor(mx, 16));
            mx = fmaxf(mx, __shfl_xor(mx, 32));
            float mnew = fmaxf(m0, mx);
            float al = exp2f(m0 - mnew);
            m0 = mnew;
            float rs = 0.f;
#pragma unroll
            for (int m = 0; m < 4; m++) {
                float p0 = exp2f(s0[m][0] - mnew);
                float p1 = exp2f(s0[m][1] - mnew);
                float p2 = exp2f(s0[m][2] - mnew);
                float p3 = exp2f(s0[m][3] - mnew);
                rs += (p0 + p1) + (p2 + p3);
                half4 t;
                t[0] = (_Float16)p0; t[1] = (_Float16)p1;
                t[2] = (_Float16)p2; t[3] = (_Float16)p3;
                pf0[m] = t;
            }
            rs += __shfl_xor(rs, 16);
            rs += __shfl_xor(rs, 32);
            l0 = l0 * al + rs;
#pragma unroll
            for (int dt = 0; dt < 4; dt++) o0[dt] *= al;
        }
        {
            float mx = s1[0][0];
#pragma unroll
            for (int m = 0; m < 4; m++)
#pragma unroll
                for (int r = 0; r < 4; r++) mx = fmaxf(mx, s1[m][r]);
            mx = fmaxf(mx, __shfl_xor(mx, 16));
            mx = fmaxf(mx, __shfl_xor(mx, 32));
            float mnew = fmaxf(m1, mx);
            float al = exp2f(m1 - mnew);
            m1 = mnew;
            float rs = 0.f;
#pragma unroll
            for (int m = 0; m < 4; m++) {
                float p0 = exp2f(s1[m][0] - mnew);
                float p1 = exp2f(s1[m][1] - mnew);
                float p2 = exp2f(s1[m][2] - mnew);
                float p3 = exp2f(s1[m][3] - mnew);
                rs += (p0 + p1) + (p2 + p3);
                half4 t;
                t[0] = (_Float16)p0; t[1] = (_Float16)p1;
                t[2] = (_Float16)p2; t[3] = (_Float16)p3;
                pf1[m] = t;
            }
            rs += __shfl_xor(rs, 16);
            rs += __shfl_xor(rs, 32);
            l1 = l1 * al + rs;
#pragma unroll
            for (int dt = 0; dt < 4; dt++) o1[dt] *= al;
        }

        // ---- O^T += V^T * P^T : V-frags shared across both q-groups ----
#pragma unroll
        for (int dt = 0; dt < 4; dt++) {
            const _Float16* vr = &Vt[dt * 16 + lc][quad * 4];
#pragma unroll
            for (int m = 0; m < 4; m++) {
                half4 va = *(const half4*)(vr + m * 16);  // keys m*16+quad*4+{0..3}
                o0[dt] = __builtin_amdgcn_mfma_f32_16x16x16f16(va, pf0[m], o0[dt], 0, 0, 0);
                o1[dt] = __builtin_amdgcn_mfma_f32_16x16x16f16(va, pf1[m], o1[dt], 0, 0, 0);
            }
        }
    }

    // epilogue: O^T reg (dt, r) -> dim = dt*16 + quad*4 + r, t = q{0,1}row
    const int b = bh >> 4, h = bh & 15;
    {
        float inv = 1.0f / l0;
        size_t base = ((size_t)(b * TT + q0row)) * CC + h * HD;
#pragma unroll
        for (int dt = 0; dt < 4; dt++) {
            half4 hv;
#pragma unroll
            for (int r = 0; r < 4; r++) hv[r] = (_Float16)(o0[dt][r] * inv);
            *(half4*)(Op + base + dt * 16 + quad * 4) = hv;
        }
    }
    {
        float inv = 1.0f / l1;
        size_t base = ((size_t)(b * TT + q1row)) * CC + h * HD;
#pragma unroll
        for (int dt = 0; dt < 4; dt++) {
            half4 hv;
#pragma unroll
            for (int r = 0; r < 4; r++) hv[r] = (_Float16)(o1[dt][r] * inv);
            *(half4*)(Op + base + dt * 16 + quad * 4) = hv;
        }
    }
}

// ---------------------------------------------------------------------------
extern "C" void kernel_launch(void* const* d_in, const int* in_sizes, int n_in,
                              void* d_out, int out_size, void* d_ws, size_t ws_size,
                              hipStream_t stream) {
    const float* x      = (const float*)d_in[0];  // [B,T,C]
    const float* W_attn = (const float*)d_in[1];  // [3C,C]
    const float* b_attn = (const float*)d_in[2];  // [3C]
    const float* W_proj = (const float*)d_in[3];  // [C,C]
    const float* b_proj = (const float*)d_in[4];  // [C]
    float* out = (float*)d_out;

    const size_t SZ_XH  = (size_t)BB * TT * CC * 2;
    const size_t SZ_WA  = (size_t)3 * CC * CC * 2;
    const size_t SZ_WP  = (size_t)CC * CC * 2;
    const size_t SZ_QKV = (size_t)BB * HH * TT * HD * 2;
    size_t off = 0;
    _Float16* xh  = (_Float16*)((char*)d_ws + off); off += SZ_XH;
    _Float16* wah = (_Float16*)((char*)d_ws + off); off += SZ_WA;
    _Float16* wph = (_Float16*)((char*)d_ws + off); off += SZ_WP;
    _Float16* Qh  = (_Float16*)((char*)d_ws + off); off += SZ_QKV;
    _Float16* Kh  = (_Float16*)((char*)d_ws + off); off += SZ_QKV;
    _Float16* Vh  = (_Float16*)((char*)d_ws + off); off += SZ_QKV;
    _Float16* Ah  = (_Float16*)((char*)d_ws + off); off += SZ_XH;
    if (ws_size < off) return;

    const int NX  = BB * TT * CC;
    const int NWA = 3 * CC * CC;
    const int NWP = CC * CC;
    cvt_f32_f16<<<NX / 8 / 256, 256, 0, stream>>>(x, xh, NX);
    cvt_f32_f16<<<NWA / 8 / 256, 256, 0, stream>>>(W_attn, wah, NWA);
    cvt_f32_f16<<<NWP / 8 / 256, 256, 0, stream>>>(W_proj, wph, NWP);

    hgemm_nt<0><<<dim3(3 * CC / 128, BB * TT / 128), 256, 0, stream>>>(
        xh, wah, b_attn, Qh, Kh, Vh, nullptr, BB * TT, 3 * CC, CC);

    attn_flash<<<dim3(BB * HH, TT / 256), 512, 0, stream>>>(Qh, Kh, Vh, Ah);

    hgemm_nt<1><<<dim3(CC / 128, BB * TT / 128), 256, 0, stream>>>(
        Ah, wph, b_proj, nullptr, nullptr, nullptr, out, BB * TT, CC, CC);
}